// Round 4
// baseline (151.524 us; speedup 1.0000x reference)
//
#include <hip/hip_runtime.h>

typedef __attribute__((ext_vector_type(4))) float f32x4;
typedef __attribute__((ext_vector_type(4))) int   i32x4;
typedef __attribute__((ext_vector_type(8))) int   i32x8;

#define DIM 256
#define D4  64    // float4 per row

// async global->LDS, 16B per lane; LDS dest = wave-uniform base + lane*16.
#define GLD_LDS16(g, l) __builtin_amdgcn_global_load_lds(                      \
    (const __attribute__((address_space(1))) void*)(g),                        \
    (__attribute__((address_space(3))) void*)(l), 16, 0, 0)

// ---------------------------------------------------------------------------
// fp8 rows are PLAIN byte-k order (256 B/row). MX 16x16x128 A/B frag layout
// (m148 pattern): m = lane&15, k = (lane>>4)*32 + j, j=0..31 -> lane needs the
// two 16B chunks {q*2, q*2+1} of each 128-wide K block. Staging XORs the 16B
// chunk index with (row&15) so 8-lane ds_read phases hit 8 distinct bank
// groups (conflict-free; R2 measured 0 with this family of swizzle).
// ---------------------------------------------------------------------------

// One wave per row. Rows [0,N): exact fp32 pos_sim -> posPart[row] (no
// single-address atomic: that was R1's 110us) + normalized pk -> fp8 e4m3.
// Rows [N,N+M): normalized nv -> fp8.
__global__ __launch_bounds__(256) void normalize_kernel(
    const float4* __restrict__ pk, const float4* __restrict__ pv,
    const float4* __restrict__ nv, unsigned int* __restrict__ pkn,
    unsigned int* __restrict__ nvn, float* __restrict__ posPart, int N) {
  int row  = blockIdx.x * 4 + (threadIdx.x >> 6);
  int lane = threadIdx.x & 63;
  if (row < N) {
    float4 x = pk[row * D4 + lane];
    float4 y = pv[row * D4 + lane];
    float skk = x.x*x.x + x.y*x.y + x.z*x.z + x.w*x.w;
    float svv = y.x*y.x + y.y*y.y + y.z*y.z + y.w*y.w;
    float skv = x.x*y.x + x.y*y.y + x.z*y.z + x.w*y.w;
#pragma unroll
    for (int m = 32; m >= 1; m >>= 1) {
      skk += __shfl_xor(skk, m, 64);
      svv += __shfl_xor(svv, m, 64);
      skv += __shfl_xor(skv, m, 64);
    }
    float nk  = fmaxf(sqrtf(skk), 1e-8f);
    float nvv = fmaxf(sqrtf(svv), 1e-8f);
    if (lane == 0) posPart[row] = skv / (nk * nvv);
    float rk = 1.0f / nk;
    int w = __builtin_amdgcn_cvt_pk_fp8_f32(x.x * rk, x.y * rk, 0, false);
    w = __builtin_amdgcn_cvt_pk_fp8_f32(x.z * rk, x.w * rk, w, true);
    pkn[(size_t)row * 64 + lane] = (unsigned int)w;   // plain byte-k order
  } else {
    int r2 = row - N;
    float4 x = nv[r2 * D4 + lane];
    float s = x.x*x.x + x.y*x.y + x.z*x.z + x.w*x.w;
#pragma unroll
    for (int m = 32; m >= 1; m >>= 1) s += __shfl_xor(s, m, 64);
    float rn = 1.0f / fmaxf(sqrtf(s), 1e-8f);
    int w = __builtin_amdgcn_cvt_pk_fp8_f32(x.x * rn, x.y * rn, 0, false);
    w = __builtin_amdgcn_cvt_pk_fp8_f32(x.z * rn, x.w * rn, w, true);
    nvn[(size_t)r2 * 64 + lane] = (unsigned int)w;
  }
}

// Fused fp8 GEMM + exp(sim/2) + row-sum, MX-scaled MFMA (unit e8m0 scales ->
// numerically identical to non-scaled fp8, 2x the rate: 4661 vs 2047 TF).
// WG 256 = 4 waves (2x2 of 64x64 wave tiles, each 4x4 of 16x16x128 MFMA).
// WG tile 128x128, full K=256 staged once (64KB LDS), ONE barrier, then
// 32 MFMA/wave with zero barriers. Epilogue = R2's shuffle reduction
// (R3's LDS epi scratch caused 2.88M bank-conflict cycles; shuffles are free).
__global__ __launch_bounds__(256, 2) void gemm_lse_kernel(
    const unsigned char* __restrict__ gA, const unsigned char* __restrict__ gB,
    float* __restrict__ rowsum) {
  __shared__ unsigned char smem[65536];
  unsigned char* As = smem;            // [128 rows][16 chunks of 16B, XOR-swizzled]
  unsigned char* Bs = smem + 32768;

  const int tid  = threadIdx.x;
  const int lane = tid & 63;
  const int wv   = tid >> 6;
  const int wm   = wv >> 1, wn = wv & 1;
  const int l15  = lane & 15, q = lane >> 4;
  const int row0 = blockIdx.y * 128;
  const int col0 = blockIdx.x * 128;
  const float kLog2eHalf = 0.72134752044448170f;  // log2(e)/2
  const int kUnitScale = 0x7F7F7F7F;              // e8m0 127 = 2^0 in every byte

  // ---- stage A and B: 4096 chunks of 16B, 16 per thread, one drain ----
#pragma unroll
  for (int i = 0; i < 8; i++) {
    int c   = i * 256 + tid;           // chunk 0..2047; 16 consecutive lanes = 1 row
    int r   = c >> 4;
    int src = ((c & 15) ^ (r & 15)) << 4;   // source-side swizzle (coalesced: same 256B row)
    GLD_LDS16(gA + (size_t)(row0 + r) * 256 + src, As + c * 16);
  }
#pragma unroll
  for (int i = 0; i < 8; i++) {
    int c   = i * 256 + tid;
    int r   = c >> 4;
    int src = ((c & 15) ^ (r & 15)) << 4;
    GLD_LDS16(gB + (size_t)(col0 + r) * 256 + src, Bs + c * 16);
  }
  __syncthreads();

  f32x4 acc[4][4];
#pragma unroll
  for (int mi = 0; mi < 4; mi++)
#pragma unroll
    for (int ni = 0; ni < 4; ni++) acc[mi][ni] = (f32x4){0.f, 0.f, 0.f, 0.f};

  // ---- K loop: 2 x K=128 blocks, 32 MFMA/wave, zero barriers ----
#pragma unroll
  for (int kb = 0; kb < 2; kb++) {
    i32x8 af[4], bf[4];
#pragma unroll
    for (int mi = 0; mi < 4; mi++) {
      int r  = wm * 64 + mi * 16 + l15;
      int c0 = (kb * 8 + q * 2)     ^ (r & 15);
      int c1 = (kb * 8 + q * 2 + 1) ^ (r & 15);
      i32x4 lo = *(const i32x4*)(As + r * 256 + c0 * 16);
      i32x4 hi = *(const i32x4*)(As + r * 256 + c1 * 16);
      af[mi] = (i32x8){lo.x, lo.y, lo.z, lo.w, hi.x, hi.y, hi.z, hi.w};
    }
#pragma unroll
    for (int ni = 0; ni < 4; ni++) {
      int r  = wn * 64 + ni * 16 + l15;
      int c0 = (kb * 8 + q * 2)     ^ (r & 15);
      int c1 = (kb * 8 + q * 2 + 1) ^ (r & 15);
      i32x4 lo = *(const i32x4*)(Bs + r * 256 + c0 * 16);
      i32x4 hi = *(const i32x4*)(Bs + r * 256 + c1 * 16);
      bf[ni] = (i32x8){lo.x, lo.y, lo.z, lo.w, hi.x, hi.y, hi.z, hi.w};
    }
#pragma unroll
    for (int mi = 0; mi < 4; mi++)
#pragma unroll
      for (int ni = 0; ni < 4; ni++)
        acc[mi][ni] = __builtin_amdgcn_mfma_scale_f32_16x16x128_f8f6f4(
            af[mi], bf[ni], acc[mi][ni],
            0, 0,                      // cbsz=fp8(e4m3), blgp=fp8(e4m3)
            0, kUnitScale,             // opsel_a, scale_a (all 1.0)
            0, kUnitScale);            // opsel_b, scale_b (all 1.0)
  }

  // ---- epilogue: exp2(sim*log2e/2), shuffle row-sums, one atomic/row ----
  // C/D layout (verified in R2/R3): col = lane&15, row = quad*4 + rr.
#pragma unroll
  for (int mi = 0; mi < 4; mi++)
#pragma unroll
    for (int rr = 0; rr < 4; rr++) {
      float v = 0.f;
#pragma unroll
      for (int ni = 0; ni < 4; ni++)
        v += __builtin_amdgcn_exp2f(acc[mi][ni][rr] * kLog2eHalf);
      v += __shfl_xor(v, 1, 16);
      v += __shfl_xor(v, 2, 16);
      v += __shfl_xor(v, 4, 16);
      v += __shfl_xor(v, 8, 16);
      if (l15 == 0)
        atomicAdd(&rowsum[row0 + wm * 64 + mi * 16 + q * 4 + rr], v);
    }
}

// out = mean(ln(rowsum)) - 0.5*mean(posPart); v_log_f32 is log2 -> scale by ln2.
__global__ __launch_bounds__(256) void finalize_kernel(
    const float* __restrict__ rowsum, const float* __restrict__ posPart,
    float* __restrict__ out, int N, float invN) {
  int idx    = blockIdx.x * blockDim.x + threadIdx.x;
  int stride = gridDim.x * blockDim.x;
  float slog = 0.f, spos = 0.f;
  for (int i = idx; i < N; i += stride) {
    slog += __builtin_amdgcn_logf(rowsum[i]);
    spos += posPart[i];
  }
#pragma unroll
  for (int m = 32; m >= 1; m >>= 1) {
    slog += __shfl_xor(slog, m, 64);
    spos += __shfl_xor(spos, m, 64);
  }
  if ((threadIdx.x & 63) == 0)
    atomicAdd(out, (slog * 0.69314718055994531f - 0.5f * spos) * invN);
}

extern "C" void kernel_launch(void* const* d_in, const int* in_sizes, int n_in,
                              void* d_out, int out_size, void* d_ws, size_t ws_size,
                              hipStream_t stream) {
  const float* pk = (const float*)d_in[0];
  const float* pv = (const float*)d_in[1];
  const float* nv = (const float*)d_in[2];
  int N = in_sizes[0] / DIM;   // 8192
  int M = in_sizes[2] / DIM;   // 8192
  float* out = (float*)d_out;

  unsigned char* pkn = (unsigned char*)d_ws;                   // [N,256] fp8 plain
  unsigned char* nvn = pkn + (size_t)N * DIM;                  // [M,256] fp8 plain
  float* rowsum  = (float*)(nvn + (size_t)M * DIM);            // [N] fp32
  float* posPart = rowsum + N;                                 // [N] fp32

  hipMemsetAsync(out, 0, sizeof(float), stream);
  hipMemsetAsync(rowsum, 0, (size_t)N * sizeof(float), stream);

  normalize_kernel<<<(N + M) / 4, 256, 0, stream>>>(
      (const float4*)pk, (const float4*)pv, (const float4*)nv,
      (unsigned int*)pkn, (unsigned int*)nvn, posPart, N);

  gemm_lse_kernel<<<dim3(M / 128, N / 128), 256, 0, stream>>>(
      pkn, nvn, rowsum);

  finalize_kernel<<<8, 256, 0, stream>>>(rowsum, posPart, out, N, 1.0f / (float)N);
}

// Round 5
// 136.133 us; speedup vs baseline: 1.1131x; 1.1131x over previous
//
#include <hip/hip_runtime.h>

typedef __attribute__((ext_vector_type(4))) float f32x4;
typedef __attribute__((ext_vector_type(4))) int   i32x4;
typedef __attribute__((ext_vector_type(8))) int   i32x8;

#define DIM 256
#define D4  64    // float4 per row

// async global->LDS, 16B per lane; LDS dest = wave-uniform base + lane*16.
#define GLD_LDS16(g, l) __builtin_amdgcn_global_load_lds(                      \
    (const __attribute__((address_space(1))) void*)(g),                        \
    (__attribute__((address_space(3))) void*)(l), 16, 0, 0)

// One wave per row. Rows [0,N): exact fp32 pos_sim -> posPart[row] + normalized
// pk -> fp8 e4m3 (plain byte-k order). Rows [N,N+M): normalized nv -> fp8.
__global__ __launch_bounds__(256) void normalize_kernel(
    const float4* __restrict__ pk, const float4* __restrict__ pv,
    const float4* __restrict__ nv, unsigned int* __restrict__ pkn,
    unsigned int* __restrict__ nvn, float* __restrict__ posPart, int N) {
  int row  = blockIdx.x * 4 + (threadIdx.x >> 6);
  int lane = threadIdx.x & 63;
  if (row < N) {
    float4 x = pk[row * D4 + lane];
    float4 y = pv[row * D4 + lane];
    float skk = x.x*x.x + x.y*x.y + x.z*x.z + x.w*x.w;
    float svv = y.x*y.x + y.y*y.y + y.z*y.z + y.w*y.w;
    float skv = x.x*y.x + x.y*y.y + x.z*y.z + x.w*y.w;
#pragma unroll
    for (int m = 32; m >= 1; m >>= 1) {
      skk += __shfl_xor(skk, m, 64);
      svv += __shfl_xor(svv, m, 64);
      skv += __shfl_xor(skv, m, 64);
    }
    float nk  = fmaxf(sqrtf(skk), 1e-8f);
    float nvv = fmaxf(sqrtf(svv), 1e-8f);
    if (lane == 0) posPart[row] = skv / (nk * nvv);
    float rk = 1.0f / nk;
    int w = __builtin_amdgcn_cvt_pk_fp8_f32(x.x * rk, x.y * rk, 0, false);
    w = __builtin_amdgcn_cvt_pk_fp8_f32(x.z * rk, x.w * rk, w, true);
    pkn[(size_t)row * 64 + lane] = (unsigned int)w;
  } else {
    int r2 = row - N;
    float4 x = nv[r2 * D4 + lane];
    float s = x.x*x.x + x.y*x.y + x.z*x.z + x.w*x.w;
#pragma unroll
    for (int m = 32; m >= 1; m >>= 1) s += __shfl_xor(s, m, 64);
    float rn = 1.0f / fmaxf(sqrtf(s), 1e-8f);
    int w = __builtin_amdgcn_cvt_pk_fp8_f32(x.x * rn, x.y * rn, 0, false);
    w = __builtin_amdgcn_cvt_pk_fp8_f32(x.z * rn, x.w * rn, w, true);
    nvn[(size_t)r2 * 64 + lane] = (unsigned int)w;
  }
}

// Fused fp8 GEMM (MX 16x16x128, unit scales = exact fp8) + exp(sim/2) + row-sum.
// R5 changes vs R4 (82us, MfmaUtil 7.9%, stall-dominated at 2 WG/CU):
//  - K split into 2 halves of 128: LDS 32KB (was 64KB) -> ~3 WGs/CU resident,
//    so one WG's stage/drain overlaps others' MFMA (m114 co-scheduling).
//  - Epilogue writes per-(WG,wave-col) partials with ONE coalesced 256B store
//    per wave -> zero global atomics (R4's 1M cross-XCD atomics wrote 16MB HBM).
// WG 256 thr = 4 waves (2x2 of 64x64), tile 128x128, grid (M/128, N/128).
__global__ __launch_bounds__(256, 3) void gemm_lse_kernel(
    const unsigned char* __restrict__ gA, const unsigned char* __restrict__ gB,
    float* __restrict__ partial, int N) {
  __shared__ unsigned char As[16384];  // [128 rows][8 chunks of 16B, XOR-swizzled]
  __shared__ unsigned char Bs[16384];

  const int tid  = threadIdx.x;
  const int lane = tid & 63;
  const int wv   = tid >> 6;
  const int wm   = wv >> 1, wn = wv & 1;
  const int l15  = lane & 15, q = lane >> 4;
  const int row0 = blockIdx.y * 128;
  const int col0 = blockIdx.x * 128;
  const float kLog2eHalf = 0.72134752044448170f;  // log2(e)/2
  const int kUnitScale = 0x7F7F7F7F;              // e8m0 127 = 2^0 per byte

  f32x4 acc[4][4];
#pragma unroll
  for (int mi = 0; mi < 4; mi++)
#pragma unroll
    for (int ni = 0; ni < 4; ni++) acc[mi][ni] = (f32x4){0.f, 0.f, 0.f, 0.f};

#pragma unroll
  for (int kb = 0; kb < 2; kb++) {
    if (kb) __syncthreads();           // protect LDS before overwrite
    // stage this K-half: 1024 chunks each matrix, 4 per thread each.
    // LDS[r][ch] = global chunk (ch ^ (r&7)); 8 lanes cover one row's 128B.
#pragma unroll
    for (int i = 0; i < 4; i++) {
      int c  = i * 256 + tid;
      int r  = c >> 3;
      int sc = ((c & 7) ^ (r & 7)) << 4;
      GLD_LDS16(gA + (size_t)(row0 + r) * 256 + kb * 128 + sc, As + c * 16);
      GLD_LDS16(gB + (size_t)(col0 + r) * 256 + kb * 128 + sc, Bs + c * 16);
    }
    __syncthreads();

    // frags: lane (l15,q) needs global chunks {2q, 2q+1} of the half.
    i32x8 bf[4];
#pragma unroll
    for (int ni = 0; ni < 4; ni++) {
      int r  = wn * 64 + ni * 16 + l15;
      int c0 = (q * 2)     ^ (r & 7);
      int c1 = (q * 2 + 1) ^ (r & 7);
      i32x4 lo = *(const i32x4*)(Bs + r * 128 + c0 * 16);
      i32x4 hi = *(const i32x4*)(Bs + r * 128 + c1 * 16);
      bf[ni] = (i32x8){lo.x, lo.y, lo.z, lo.w, hi.x, hi.y, hi.z, hi.w};
    }
#pragma unroll
    for (int mi = 0; mi < 4; mi++) {
      int r  = wm * 64 + mi * 16 + l15;
      int c0 = (q * 2)     ^ (r & 7);
      int c1 = (q * 2 + 1) ^ (r & 7);
      i32x4 lo = *(const i32x4*)(As + r * 128 + c0 * 16);
      i32x4 hi = *(const i32x4*)(As + r * 128 + c1 * 16);
      i32x8 af = (i32x8){lo.x, lo.y, lo.z, lo.w, hi.x, hi.y, hi.z, hi.w};
#pragma unroll
      for (int ni = 0; ni < 4; ni++)
        acc[mi][ni] = __builtin_amdgcn_mfma_scale_f32_16x16x128_f8f6f4(
            af, bf[ni], acc[mi][ni],
            0, 0,                      // cbsz/blgp = fp8 e4m3
            0, kUnitScale, 0, kUnitScale);
    }
  }

  // ---- epilogue: exp2(sim*log2e/2); butterfly over the 16 lane-cols gives
  // every lane the row sum; lane keeps (mi,rr) == (l15>>2, l15&3) so the wave
  // emits ONE dense coalesced 256B store. No atomics.
  // C/D layout (verified R2-R4): col = lane&15, row = quad*4 + rr.
  float keep = 0.f;
#pragma unroll
  for (int mi = 0; mi < 4; mi++)
#pragma unroll
    for (int rr = 0; rr < 4; rr++) {
      float v = 0.f;
#pragma unroll
      for (int ni = 0; ni < 4; ni++)
        v += __builtin_amdgcn_exp2f(acc[mi][ni][rr] * kLog2eHalf);
      v += __shfl_xor(v, 1, 16);
      v += __shfl_xor(v, 2, 16);
      v += __shfl_xor(v, 4, 16);
      v += __shfl_xor(v, 8, 16);
      if (l15 == mi * 4 + rr) keep = v;
    }
  // lane (q,l15) holds row (l15>>2)*16 + q*4 + (l15&3) of its wave's 64-row stripe
  int lrow = (l15 >> 2) * 16 + q * 4 + (l15 & 3);
  partial[(size_t)(blockIdx.x * 2 + wn) * N + row0 + wm * 64 + lrow] = keep;
}

// out = mean(ln(sum_j partial[j][row])) - 0.5*mean(posPart).
// One thread per row; reads coalesce across threads for each slab j.
__global__ __launch_bounds__(256) void finalize_kernel(
    const float* __restrict__ partial, const float* __restrict__ posPart,
    float* __restrict__ out, int N, int nSlabs, float invN) {
  int row = blockIdx.x * 256 + threadIdx.x;
  float s = 0.f;
  for (int j = 0; j < nSlabs; j++) s += partial[(size_t)j * N + row];
  float v = __builtin_amdgcn_logf(s) * 0.69314718055994531f - 0.5f * posPart[row];
#pragma unroll
  for (int m = 32; m >= 1; m >>= 1) v += __shfl_xor(v, m, 64);
  if ((threadIdx.x & 63) == 0) atomicAdd(out, v * invN);
}

extern "C" void kernel_launch(void* const* d_in, const int* in_sizes, int n_in,
                              void* d_out, int out_size, void* d_ws, size_t ws_size,
                              hipStream_t stream) {
  const float* pk = (const float*)d_in[0];
  const float* pv = (const float*)d_in[1];
  const float* nv = (const float*)d_in[2];
  int N = in_sizes[0] / DIM;   // 8192
  int M = in_sizes[2] / DIM;   // 8192
  float* out = (float*)d_out;

  unsigned char* pkn = (unsigned char*)d_ws;                   // [N,256] fp8
  unsigned char* nvn = pkn + (size_t)N * DIM;                  // [M,256] fp8
  float* partial = (float*)(nvn + (size_t)M * DIM);            // [M/64][N] fp32
  float* posPart = partial + (size_t)(M / 64) * N;             // [N] fp32

  hipMemsetAsync(out, 0, sizeof(float), stream);

  normalize_kernel<<<(N + M) / 4, 256, 0, stream>>>(
      (const float4*)pk, (const float4*)pv, (const float4*)nv,
      (unsigned int*)pkn, (unsigned int*)nvn, posPart, N);

  gemm_lse_kernel<<<dim3(M / 128, N / 128), 256, 0, stream>>>(
      pkn, nvn, partial, N);

  finalize_kernel<<<N / 256, 256, 0, stream>>>(
      partial, posPart, out, N, M / 64, 1.0f / (float)N);
}

// Round 6
// 106.939 us; speedup vs baseline: 1.4169x; 1.2730x over previous
//
#include <hip/hip_runtime.h>

typedef __attribute__((ext_vector_type(4))) float f32x4;
typedef __attribute__((ext_vector_type(4))) int   i32x4;
typedef __attribute__((ext_vector_type(8))) int   i32x8;

#define DIM 256
#define D4  64    // float4 per row

// async global->LDS, 16B per lane; LDS dest = wave-uniform base + lane*16.
#define GLD_LDS16(g, l) __builtin_amdgcn_global_load_lds(                      \
    (const __attribute__((address_space(1))) void*)(g),                        \
    (__attribute__((address_space(3))) void*)(l), 16, 0, 0)

// One wave per row. Rows [0,N): exact fp32 pos_sim -> posPart[row] + normalized
// pk -> fp8 e4m3 (plain byte-k order). Rows [N,N+M): normalized nv -> fp8.
__global__ __launch_bounds__(256) void normalize_kernel(
    const float4* __restrict__ pk, const float4* __restrict__ pv,
    const float4* __restrict__ nv, unsigned int* __restrict__ pkn,
    unsigned int* __restrict__ nvn, float* __restrict__ posPart, int N) {
  int row  = blockIdx.x * 4 + (threadIdx.x >> 6);
  int lane = threadIdx.x & 63;
  if (row < N) {
    float4 x = pk[row * D4 + lane];
    float4 y = pv[row * D4 + lane];
    float skk = x.x*x.x + x.y*x.y + x.z*x.z + x.w*x.w;
    float svv = y.x*y.x + y.y*y.y + y.z*y.z + y.w*y.w;
    float skv = x.x*y.x + x.y*y.y + x.z*y.z + x.w*y.w;
#pragma unroll
    for (int m = 32; m >= 1; m >>= 1) {
      skk += __shfl_xor(skk, m, 64);
      svv += __shfl_xor(svv, m, 64);
      skv += __shfl_xor(skv, m, 64);
    }
    float nk  = fmaxf(sqrtf(skk), 1e-8f);
    float nvv = fmaxf(sqrtf(svv), 1e-8f);
    if (lane == 0) posPart[row] = skv / (nk * nvv);
    float rk = 1.0f / nk;
    int w = __builtin_amdgcn_cvt_pk_fp8_f32(x.x * rk, x.y * rk, 0, false);
    w = __builtin_amdgcn_cvt_pk_fp8_f32(x.z * rk, x.w * rk, w, true);
    pkn[(size_t)row * 64 + lane] = (unsigned int)w;
  } else {
    int r2 = row - N;
    float4 x = nv[r2 * D4 + lane];
    float s = x.x*x.x + x.y*x.y + x.z*x.z + x.w*x.w;
#pragma unroll
    for (int m = 32; m >= 1; m >>= 1) s += __shfl_xor(s, m, 64);
    float rn = 1.0f / fmaxf(sqrtf(s), 1e-8f);
    int w = __builtin_amdgcn_cvt_pk_fp8_f32(x.x * rn, x.y * rn, 0, false);
    w = __builtin_amdgcn_cvt_pk_fp8_f32(x.z * rn, x.w * rn, w, true);
    nvn[(size_t)r2 * 64 + lane] = (unsigned int)w;
  }
}

// Fused fp8 GEMM (MX 16x16x128, unit scales = exact fp8) + exp(sim/2) + row-sum.
// UNCHANGED from R5 (it dropped below the 43us fill dispatches in top-5).
// WG 256 thr = 4 waves (2x2 of 64x64), tile 128x128, grid (M/128, N/128).
__global__ __launch_bounds__(256, 3) void gemm_lse_kernel(
    const unsigned char* __restrict__ gA, const unsigned char* __restrict__ gB,
    float* __restrict__ partial, int N) {
  __shared__ unsigned char As[16384];  // [128 rows][8 chunks of 16B, XOR-swizzled]
  __shared__ unsigned char Bs[16384];

  const int tid  = threadIdx.x;
  const int lane = tid & 63;
  const int wv   = tid >> 6;
  const int wm   = wv >> 1, wn = wv & 1;
  const int l15  = lane & 15, q = lane >> 4;
  const int row0 = blockIdx.y * 128;
  const int col0 = blockIdx.x * 128;
  const float kLog2eHalf = 0.72134752044448170f;  // log2(e)/2
  const int kUnitScale = 0x7F7F7F7F;              // e8m0 127 = 2^0 per byte

  f32x4 acc[4][4];
#pragma unroll
  for (int mi = 0; mi < 4; mi++)
#pragma unroll
    for (int ni = 0; ni < 4; ni++) acc[mi][ni] = (f32x4){0.f, 0.f, 0.f, 0.f};

#pragma unroll
  for (int kb = 0; kb < 2; kb++) {
    if (kb) __syncthreads();           // protect LDS before overwrite
#pragma unroll
    for (int i = 0; i < 4; i++) {
      int c  = i * 256 + tid;
      int r  = c >> 3;
      int sc = ((c & 7) ^ (r & 7)) << 4;
      GLD_LDS16(gA + (size_t)(row0 + r) * 256 + kb * 128 + sc, As + c * 16);
      GLD_LDS16(gB + (size_t)(col0 + r) * 256 + kb * 128 + sc, Bs + c * 16);
    }
    __syncthreads();

    i32x8 bf[4];
#pragma unroll
    for (int ni = 0; ni < 4; ni++) {
      int r  = wn * 64 + ni * 16 + l15;
      int c0 = (q * 2)     ^ (r & 7);
      int c1 = (q * 2 + 1) ^ (r & 7);
      i32x4 lo = *(const i32x4*)(Bs + r * 128 + c0 * 16);
      i32x4 hi = *(const i32x4*)(Bs + r * 128 + c1 * 16);
      bf[ni] = (i32x8){lo.x, lo.y, lo.z, lo.w, hi.x, hi.y, hi.z, hi.w};
    }
#pragma unroll
    for (int mi = 0; mi < 4; mi++) {
      int r  = wm * 64 + mi * 16 + l15;
      int c0 = (q * 2)     ^ (r & 7);
      int c1 = (q * 2 + 1) ^ (r & 7);
      i32x4 lo = *(const i32x4*)(As + r * 128 + c0 * 16);
      i32x4 hi = *(const i32x4*)(As + r * 128 + c1 * 16);
      i32x8 af = (i32x8){lo.x, lo.y, lo.z, lo.w, hi.x, hi.y, hi.z, hi.w};
#pragma unroll
      for (int ni = 0; ni < 4; ni++)
        acc[mi][ni] = __builtin_amdgcn_mfma_scale_f32_16x16x128_f8f6f4(
            af, bf[ni], acc[mi][ni],
            0, 0, 0, kUnitScale, 0, kUnitScale);
    }
  }

  // epilogue: exp2(sim*log2e/2); butterfly; one dense 256B store/wave, no atomics.
  float keep = 0.f;
#pragma unroll
  for (int mi = 0; mi < 4; mi++)
#pragma unroll
    for (int rr = 0; rr < 4; rr++) {
      float v = 0.f;
#pragma unroll
      for (int ni = 0; ni < 4; ni++)
        v += __builtin_amdgcn_exp2f(acc[mi][ni][rr] * kLog2eHalf);
      v += __shfl_xor(v, 1, 16);
      v += __shfl_xor(v, 2, 16);
      v += __shfl_xor(v, 4, 16);
      v += __shfl_xor(v, 8, 16);
      if (l15 == mi * 4 + rr) keep = v;
    }
  int lrow = (l15 >> 2) * 16 + q * 4 + (l15 & 3);
  partial[(size_t)(blockIdx.x * 2 + wn) * N + row0 + wm * 64 + lrow] = keep;
}

// out = mean(ln(sum_j partial[j][row])) - 0.5*mean(posPart).
// R6 rewrite: R5 used 32 blocks (32/256 CUs busy) with a 128-deep runtime
// loop whose conservative unroll serialized ~900-cyc loads -> ~35us.
// Now: 128 blocks, 4 slab-groups x 64 rows per block, unroll-8 (8 loads in
// flight), LDS cross-group reduce. Predicted ~2-3us.
__global__ __launch_bounds__(256) void finalize_kernel(
    const float* __restrict__ partial, const float* __restrict__ posPart,
    float* __restrict__ out, int N, int slabsPerGroup, float invN) {
  __shared__ float red[4][64];
  int t  = threadIdx.x;
  int rl = t & 63, g = t >> 6;
  int row = blockIdx.x * 64 + rl;
  const float* p = partial + (size_t)(g * slabsPerGroup) * N + row;
  float s = 0.f;
#pragma unroll 8
  for (int j = 0; j < slabsPerGroup; j++) s += p[(size_t)j * N];
  red[g][rl] = s;
  __syncthreads();
  if (t < 64) {
    float tot = red[0][rl] + red[1][rl] + red[2][rl] + red[3][rl];
    float v = __builtin_amdgcn_logf(tot) * 0.69314718055994531f
              - 0.5f * posPart[row];
#pragma unroll
    for (int m = 32; m >= 1; m >>= 1) v += __shfl_xor(v, m, 64);
    if (rl == 0) atomicAdd(out, v * invN);
  }
}

extern "C" void kernel_launch(void* const* d_in, const int* in_sizes, int n_in,
                              void* d_out, int out_size, void* d_ws, size_t ws_size,
                              hipStream_t stream) {
  const float* pk = (const float*)d_in[0];
  const float* pv = (const float*)d_in[1];
  const float* nv = (const float*)d_in[2];
  int N = in_sizes[0] / DIM;   // 8192
  int M = in_sizes[2] / DIM;   // 8192
  float* out = (float*)d_out;

  unsigned char* pkn = (unsigned char*)d_ws;                   // [N,256] fp8
  unsigned char* nvn = pkn + (size_t)N * DIM;                  // [M,256] fp8
  float* partial = (float*)(nvn + (size_t)M * DIM);            // [M/64][N] fp32
  float* posPart = partial + (size_t)(M / 64) * N;             // [N] fp32

  hipMemsetAsync(out, 0, sizeof(float), stream);

  normalize_kernel<<<(N + M) / 4, 256, 0, stream>>>(
      (const float4*)pk, (const float4*)pv, (const float4*)nv,
      (unsigned int*)pkn, (unsigned int*)nvn, posPart, N);

  gemm_lse_kernel<<<dim3(M / 128, N / 128), 256, 0, stream>>>(
      pkn, nvn, partial, N);

  finalize_kernel<<<N / 64, 256, 0, stream>>>(
      partial, posPart, out, N, (M / 64) / 4, 1.0f / (float)N);
}